// Round 8
// baseline (106.568 us; speedup 1.0000x reference)
//
#include <hip/hip_runtime.h>

#define KCODES 512
#define DIM    64
#define NVEC   65536          // 64 * 32 * 32
#define TAU    0.05f          // near-tie trigger in dist/2 units (fp32 err ~3e-3)

typedef __attribute__((ext_vector_type(8))) short   short8;  // 8 bf16 = 4 VGPRs
typedef __attribute__((ext_vector_type(4))) float   f32x4;

static __device__ __forceinline__ unsigned f2bfu(float f) {  // fp32 -> bf16 RNE
    unsigned u = __builtin_bit_cast(unsigned, f);
    u += 0x7fffu + ((u >> 16) & 1u);
    return u >> 16;
}

// ---------------------------------------------------------------------------
// Prep: split codebook into bf16 hi(trunc)/lo(RNE of residual); e2q[k] =
// ||e_k||^2/2 + 256 (fp64 reduce). One 64-thread block per code.
// ---------------------------------------------------------------------------
__global__ void prep_kernel(const float* __restrict__ cb,
                            unsigned short* __restrict__ cbh,
                            unsigned short* __restrict__ cbl,
                            float* __restrict__ e2q) {
    const int k = blockIdx.x, d = threadIdx.x;
    const int e = k * DIM + d;
    float v = cb[e];
    unsigned u = __builtin_bit_cast(unsigned, v);
    float hi = __builtin_bit_cast(float, u & 0xFFFF0000u);
    cbh[e] = (unsigned short)(u >> 16);
    cbl[e] = (unsigned short)f2bfu(v - hi);
    double p = (double)v * (double)v;
#pragma unroll
    for (int off = 32; off > 0; off >>= 1) p += __shfl_down(p, off, 64);
    if (d == 0) e2q[k] = (float)(0.5 * p + 256.0);
}

// ---------------------------------------------------------------------------
// Main: block = 128 threads / 64 vectors, 2 waves; each wave ranks ALL 512
// codes for its 32 vectors (2 n-tiles). Grid = 1024 -> 4 blocks/CU: same
// per-CU throughput totals as R7 but 4 independent barrier domains so the
// staging-barrier vmcnt drains interleave across blocks (R7 was 2 domains,
// latency-bound). Codebook (bf16 hi/lo) LDS-staged 64 codes/step, dbuf.
// acc init = e2/2+256, B = -x => rank-safe dist. Exact fp32 top-2 (min/med3)
// w/ index; fp64 re-resolve of both candidates on near-tie.
// ---------------------------------------------------------------------------
__launch_bounds__(128, 2)
__global__ void vq_main(const float* __restrict__ x,
                        const float* __restrict__ cb,
                        const unsigned short* __restrict__ cbh,
                        const unsigned short* __restrict__ cbl,
                        const float* __restrict__ e2q,
                        float* __restrict__ out) {
    __shared__ unsigned short sAh[2][4096];   // [buf][qd*64+c][8]  8 KB each
    __shared__ unsigned short sAl[2][4096];
    __shared__ float sE2[KCODES];
    __shared__ int   s_i1[64], s_i2[64], s_flag[64], s_win[64];

    const int tid  = threadIdx.x;             // 0..127
    const int wave = tid >> 6;                // 0..1
    const int lane = tid & 63;
    const int quad = lane >> 4;
    const int l16  = lane & 15;

    const int v0    = blockIdx.x * 64;
    const int b     = v0 >> 10;
    const int nbase = v0 & 1023;
    const float* xb = x + (size_t)b * 65536;

    // ---- stage step 0 into regs (latency hidden behind B-frag build) -------
    short8 stg[8];
#pragma unroll
    for (int r = 0; r < 8; ++r) {
        const int idx = tid + r * 128;        // [0,1024): <512 hi, >=512 lo
        const int q  = idx & 511;
        const int c  = q >> 3, qd = q & 7;
        const unsigned short* src = (idx < 512 ? cbh : cbl) + (size_t)c * 64 + qd * 8;
        stg[r] = *(const short8*)src;
    }

    // ---- B fragments of NEGATED x: B[k=quad*8+j+32ko][n=l16], hi/lo --------
    short8 Bh[2][2], Bl[2][2];
#pragma unroll
    for (int nt = 0; nt < 2; ++nt) {
        const int n_g = nbase + wave * 32 + nt * 16 + l16;
#pragma unroll
        for (int ko = 0; ko < 2; ++ko) {
#pragma unroll
            for (int j = 0; j < 8; ++j) {
                const int d = quad * 8 + j + ko * 32;
                float f = -xb[(size_t)d * 1024 + n_g];
                unsigned u = __builtin_bit_cast(unsigned, f);
                float hi = __builtin_bit_cast(float, u & 0xFFFF0000u);
                Bh[nt][ko][j] = (short)(u >> 16);
                Bl[nt][ko][j] = (short)f2bfu(f - hi);
            }
        }
    }

    // ---- stage e2 and step 0 into LDS --------------------------------------
    *(f32x4*)(sE2 + tid * 4) = *(const f32x4*)(e2q + tid * 4);
#pragma unroll
    for (int r = 0; r < 8; ++r) {
        const int idx = tid + r * 128;
        const int q  = idx & 511;
        const int c  = q >> 3, qd = q & 7;
        unsigned short* dst = (idx < 512 ? sAh[0] : sAl[0]) + (qd * 64 + c) * 8;
        *(short8*)dst = stg[r];
    }
    __syncthreads();

    float f1[2] = {1e30f, 1e30f}, f2_[2] = {1e30f, 1e30f};
    int   i1[2] = {0, 0},         i2_[2] = {0, 0};

#pragma unroll 1
    for (int s = 0; s < 8; ++s) {
        // prefetch step s+1 into regs (before compute; hidden)
        if (s < 7) {
#pragma unroll
            for (int r = 0; r < 8; ++r) {
                const int idx = tid + r * 128;
                const int q  = idx & 511;
                const int c  = q >> 3, qd = q & 7;
                const unsigned short* src =
                    (idx < 512 ? cbh : cbl) + (size_t)((s + 1) * 64 + c) * 64 + qd * 8;
                stg[r] = *(const short8*)src;
            }
        }

        // compute on buffer s&1: 4 subtiles of 16 codes
        const unsigned short* bh = sAh[s & 1];
        const unsigned short* bl = sAl[s & 1];
#pragma unroll
        for (int st = 0; st < 4; ++st) {
            const int cbase = s * 64 + st * 16;
            short8 Ah0 = *(const short8*)(bh + ( quad      * 64 + st * 16 + l16) * 8);
            short8 Ah1 = *(const short8*)(bh + ((quad + 4) * 64 + st * 16 + l16) * 8);
            short8 Al0 = *(const short8*)(bl + ( quad      * 64 + st * 16 + l16) * 8);
            short8 Al1 = *(const short8*)(bl + ((quad + 4) * 64 + st * 16 + l16) * 8);
            f32x4  e2v = *(const f32x4*)(sE2 + cbase + quad * 4);

#pragma unroll
            for (int nt = 0; nt < 2; ++nt) {
                f32x4 acc = e2v;   // = e2/2 + 256; with B = -x: rank-safe dist
                acc = __builtin_amdgcn_mfma_f32_16x16x32_bf16(Ah0, Bh[nt][0], acc, 0, 0, 0);
                acc = __builtin_amdgcn_mfma_f32_16x16x32_bf16(Ah1, Bh[nt][1], acc, 0, 0, 0);
                acc = __builtin_amdgcn_mfma_f32_16x16x32_bf16(Ah0, Bl[nt][0], acc, 0, 0, 0);
                acc = __builtin_amdgcn_mfma_f32_16x16x32_bf16(Ah1, Bl[nt][1], acc, 0, 0, 0);
                acc = __builtin_amdgcn_mfma_f32_16x16x32_bf16(Al0, Bh[nt][0], acc, 0, 0, 0);
                acc = __builtin_amdgcn_mfma_f32_16x16x32_bf16(Al1, Bh[nt][1], acc, 0, 0, 0);
#pragma unroll
                for (int r = 0; r < 4; ++r) {
                    float dd = acc[r];
                    int   id = cbase + quad * 4 + r;
                    bool  c1 = dd < f1[nt];           // strict: earlier id wins
                    bool  c2 = dd < f2_[nt];
                    i2_[nt] = c1 ? i1[nt] : (c2 ? id : i2_[nt]);
                    f2_[nt] = fminf(fmaxf(f1[nt], dd), f2_[nt]);  // med3(f1,f2,dd)
                    i1[nt]  = c1 ? id : i1[nt];
                    f1[nt]  = fminf(f1[nt], dd);
                }
            }
        }

        // publish step s+1 to the other buffer
        if (s < 7) {
#pragma unroll
            for (int r = 0; r < 8; ++r) {
                const int idx = tid + r * 128;
                const int q  = idx & 511;
                const int c  = q >> 3, qd = q & 7;
                unsigned short* dst =
                    (idx < 512 ? sAh[(s + 1) & 1] : sAl[(s + 1) & 1]) + (qd * 64 + c) * 8;
                *(short8*)dst = stg[r];
            }
        }
        __syncthreads();
    }

    // ---- cross-quad butterfly merge; each wave has full-512 top-2 ----------
#pragma unroll
    for (int nt = 0; nt < 2; ++nt) {
        float F1 = f1[nt], F2 = f2_[nt];
        int   I1 = i1[nt], I2 = i2_[nt];
#pragma unroll
        for (int delta = 16; delta <= 32; delta <<= 1) {
            float of1 = __shfl_xor(F1, delta, 64);
            int   oi1 = __shfl_xor(I1, delta, 64);
            float of2 = __shfl_xor(F2, delta, 64);
            int   oi2 = __shfl_xor(I2, delta, 64);
            bool o1_first = (of1 < F1) || (of1 == F1 && oi1 < I1);
            if (o1_first) {
                bool keep = (F1 < of2) || (F1 == of2 && I1 < oi2);
                F2 = keep ? F1 : of2;
                I2 = keep ? I1 : oi2;
                F1 = of1; I1 = oi1;
            } else {
                bool o1_second = (of1 < F2) || (of1 == F2 && oi1 < I2);
                if (o1_second) { F2 = of1; I2 = oi1; }
            }
        }
        if (quad == 0) {   // lanes 0..15 hold final result for their vector
            const int vl = wave * 32 + nt * 16 + l16;
            s_win[vl]  = I1;
            s_i1[vl]   = I1;
            s_i2[vl]   = I2;
            s_flag[vl] = (F2 - F1) < TAU;
        }
    }
    __syncthreads();

    // ---- parallel fp64 re-resolve: 2 lanes per vector, both candidates -----
    {
        const int vec = tid >> 1, sub = tid & 1;   // 64 vectors x 2 lanes
        if (s_flag[vec]) {
            const int i1c = s_i1[vec], i2c = s_i2[vec];
            const float* xr = xb + nbase + vec;
            const float* r1 = cb + (size_t)i1c * DIM;
            const float* r2 = cb + (size_t)i2c * DIM;
            double D1 = 0.0, D2 = 0.0;
#pragma unroll 4
            for (int i = 0; i < 32; ++i) {
                const int d = sub + 2 * i;
                double xd = (double)xr[(size_t)d * 1024];
                double t1 = xd - (double)r1[d]; D1 += t1 * t1;
                double t2 = xd - (double)r2[d]; D2 += t2 * t2;
            }
            D1 += __shfl_down(D1, 1, 64);
            D2 += __shfl_down(D2, 1, 64);
            if (sub == 0) {
                if (D2 < D1 || (D2 == D1 && i2c < i1c)) s_win[vec] = i2c;
            }
        }
    }
    __syncthreads();

    // ---- output: out[b, d, nbase+n] = cb[win[n]][d], coalesced over n ------
    {
        const int n    = tid & 63;            // 64 vectors
        const int dgrp = tid >> 6;            // 2 groups of 32 dims
        const float4* crow = (const float4*)(cb + (size_t)s_win[n] * DIM);
        float* op = out + (size_t)b * 65536 + nbase + n;
#pragma unroll
        for (int i = 0; i < 8; ++i) {
            const int d0 = dgrp * 32 + i * 4;
            float4 val = crow[d0 >> 2];
            op[(size_t)(d0 + 0) * 1024] = val.x;
            op[(size_t)(d0 + 1) * 1024] = val.y;
            op[(size_t)(d0 + 2) * 1024] = val.z;
            op[(size_t)(d0 + 3) * 1024] = val.w;
        }
    }
}

extern "C" void kernel_launch(void* const* d_in, const int* in_sizes, int n_in,
                              void* d_out, int out_size, void* d_ws, size_t ws_size,
                              hipStream_t stream) {
    const float* x  = (const float*)d_in[0];   // (64, 64, 32, 32) fp32
    const float* cb = (const float*)d_in[1];   // (512, 64) fp32
    float* out = (float*)d_out;

    // workspace: cb_hi (64KB) | cb_lo (64KB) | e2q (2KB)
    unsigned short* cbh = (unsigned short*)d_ws;
    unsigned short* cbl = cbh + KCODES * DIM;
    float*          e2q = (float*)(cbl + KCODES * DIM);

    prep_kernel<<<KCODES, 64, 0, stream>>>(cb, cbh, cbl, e2q);
    vq_main<<<NVEC / 64, 128, 0, stream>>>(x, cb, cbh, cbl, e2q, out);
}

// Round 9
// 90.158 us; speedup vs baseline: 1.1820x; 1.1820x over previous
//
#include <hip/hip_runtime.h>

#define KCODES 512
#define DIM    64
#define NVEC   65536          // 64 * 32 * 32
#define TAU    0.05f          // near-tie trigger in dist/2 units (fp32 err ~2e-4)

typedef __attribute__((ext_vector_type(8))) short   short8;  // 8 bf16 = 4 VGPRs
typedef __attribute__((ext_vector_type(4))) float   f32x4;

static __device__ __forceinline__ unsigned f2bfu(float f) {  // fp32 -> bf16 RNE
    unsigned u = __builtin_bit_cast(unsigned, f);
    u += 0x7fffu + ((u >> 16) & 1u);
    return u >> 16;
}

// ---------------------------------------------------------------------------
// Prep (single dispatch, 640 blocks x 64 thr):
//  blocks 0..127  : rearrange codebook into staged-tile layout cbt.
//    granule g (16 B = 8 bf16) for g = s*1024 + h*512 + qd*64 + cl holds
//    codebook[s*64+cl][qd*8 .. qd*8+8) (h=0: bf16-hi trunc, h=1: bf16-lo RNE).
//    This makes the main kernel's LDS staging a LINEAR copy (no conflicts).
//  blocks 128..639: e2q[k] = ||e_k||^2/2 + 256 (fp64 reduce).
// ---------------------------------------------------------------------------
__global__ void prep_kernel(const float* __restrict__ cb,
                            unsigned short* __restrict__ cbt,
                            float* __restrict__ e2q) {
    if (blockIdx.x < 128) {
        const int g   = blockIdx.x * 64 + threadIdx.x;   // 0..8191
        const int s   = g >> 10;
        const int rem = g & 1023;
        const int h   = rem >> 9;
        const int qd  = (rem >> 6) & 7;
        const int cl  = rem & 63;
        const float* src = cb + (size_t)(s * 64 + cl) * DIM + qd * 8;
        short8 v;
#pragma unroll
        for (int j = 0; j < 8; ++j) {
            float f = src[j];
            unsigned u = __builtin_bit_cast(unsigned, f);
            if (h == 0) {
                v[j] = (short)(u >> 16);
            } else {
                float hi = __builtin_bit_cast(float, u & 0xFFFF0000u);
                v[j] = (short)f2bfu(f - hi);
            }
        }
        *(short8*)(cbt + (size_t)g * 8) = v;
    } else {
        const int k = blockIdx.x - 128;                  // 0..511
        float v = cb[k * DIM + threadIdx.x];
        double p = (double)v * (double)v;
#pragma unroll
        for (int off = 32; off > 0; off >>= 1) p += __shfl_down(p, off, 64);
        if (threadIdx.x == 0) e2q[k] = (float)(0.5 * p + 256.0);
    }
}

// ---------------------------------------------------------------------------
// Main: block = 256 thr / 64 vectors, 4 waves; wave w ranks ALL 512 codes for
// its 16 vectors (1 n-tile). Grid = 1024 -> 4 blocks/CU (LDS 35 KB), 16
// waves/CU, 4 independent barrier domains. Codebook staged from cbt 64
// codes/step, double-buffered; staging is a linear copy (coalesced global,
// conflict-free LDS writes); fragment reads are lane-contiguous (no
// conflicts). acc init = e2/2+256, B = -x => rank-safe dist. Exact fp32
// top-2 (min/med3) w/ index; fp64 re-resolve of both candidates on near-tie.
// ---------------------------------------------------------------------------
__launch_bounds__(256, 4)
__global__ void vq_main(const float* __restrict__ x,
                        const float* __restrict__ cb,
                        const unsigned short* __restrict__ cbt,
                        const float* __restrict__ e2q,
                        float* __restrict__ out) {
    __shared__ __align__(16) unsigned short sA[2][8192];   // 16 KB per buffer
    __shared__ float sE2[KCODES];
    __shared__ int   s_i1[64], s_i2[64], s_flag[64], s_win[64];

    const int tid  = threadIdx.x;
    const int wave = tid >> 6;
    const int lane = tid & 63;
    const int quad = lane >> 4;
    const int l16  = lane & 15;

    const int v0    = blockIdx.x * 64;
    const int b     = v0 >> 10;
    const int nbase = v0 & 1023;
    const float* xb = x + (size_t)b * 65536;

    // ---- stage step-0 granules into regs (coalesced; hidden by B build) ----
    short8 stg[4];
#pragma unroll
    for (int r = 0; r < 4; ++r)
        stg[r] = *(const short8*)(cbt + (size_t)(tid + r * 256) * 8);

    // ---- B fragments of NEGATED x: B[k=quad*8+j+32ko][n=l16], hi/lo --------
    short8 Bh[2], Bl[2];
    {
        const int n_g = nbase + wave * 16 + l16;
#pragma unroll
        for (int ko = 0; ko < 2; ++ko) {
#pragma unroll
            for (int j = 0; j < 8; ++j) {
                const int d = quad * 8 + j + ko * 32;
                float f = -xb[(size_t)d * 1024 + n_g];
                unsigned u = __builtin_bit_cast(unsigned, f);
                float hi = __builtin_bit_cast(float, u & 0xFFFF0000u);
                Bh[ko][j] = (short)(u >> 16);
                Bl[ko][j] = (short)f2bfu(f - hi);
            }
        }
    }

    // ---- stage e2 + step 0 into LDS (linear copy: conflict-free) -----------
    if (tid < 128) *(f32x4*)(sE2 + tid * 4) = *(const f32x4*)(e2q + tid * 4);
#pragma unroll
    for (int r = 0; r < 4; ++r)
        *(short8*)(sA[0] + (size_t)(tid + r * 256) * 8) = stg[r];
    __syncthreads();

    float f1 = 1e30f, f2_ = 1e30f;
    int   i1 = 0,     i2_ = 0;

#pragma unroll 1
    for (int s = 0; s < 8; ++s) {
        // prefetch next step into regs (issued before compute; latency hidden)
        if (s < 7) {
#pragma unroll
            for (int r = 0; r < 4; ++r)
                stg[r] = *(const short8*)(cbt +
                          (size_t)((s + 1) * 1024 + tid + r * 256) * 8);
        }

        const unsigned short* buf = sA[s & 1];
#pragma unroll
        for (int st = 0; st < 4; ++st) {
            const int cbase = s * 64 + st * 16;
            const int roff  = quad * 64 + st * 16 + l16;   // lane-contiguous
            short8 A00 = *(const short8*)(buf + (size_t)(      roff) * 8); // hi,o0
            short8 A01 = *(const short8*)(buf + (size_t)(256 + roff) * 8); // hi,o1
            short8 A10 = *(const short8*)(buf + (size_t)(512 + roff) * 8); // lo,o0
            short8 A11 = *(const short8*)(buf + (size_t)(768 + roff) * 8); // lo,o1
            f32x4  e2v = *(const f32x4*)(sE2 + cbase + quad * 4);

            f32x4 acc = e2v;   // = e2/2 + 256; with B = -x: rank-safe dist
            acc = __builtin_amdgcn_mfma_f32_16x16x32_bf16(A00, Bh[0], acc, 0, 0, 0);
            acc = __builtin_amdgcn_mfma_f32_16x16x32_bf16(A01, Bh[1], acc, 0, 0, 0);
            acc = __builtin_amdgcn_mfma_f32_16x16x32_bf16(A00, Bl[0], acc, 0, 0, 0);
            acc = __builtin_amdgcn_mfma_f32_16x16x32_bf16(A01, Bl[1], acc, 0, 0, 0);
            acc = __builtin_amdgcn_mfma_f32_16x16x32_bf16(A10, Bh[0], acc, 0, 0, 0);
            acc = __builtin_amdgcn_mfma_f32_16x16x32_bf16(A11, Bh[1], acc, 0, 0, 0);

#pragma unroll
            for (int r = 0; r < 4; ++r) {
                float dd = acc[r];
                int   id = cbase + quad * 4 + r;
                bool  c1 = dd < f1;               // strict: earlier id wins
                bool  c2 = dd < f2_;
                i2_ = c1 ? i1 : (c2 ? id : i2_);
                f2_ = fminf(fmaxf(f1, dd), f2_);  // med3(f1, dd, f2)
                i1  = c1 ? id : i1;
                f1  = fminf(f1, dd);
            }
        }

        // publish next step (linear copy: conflict-free)
        if (s < 7) {
#pragma unroll
            for (int r = 0; r < 4; ++r)
                *(short8*)(sA[(s + 1) & 1] + (size_t)(tid + r * 256) * 8) = stg[r];
        }
        __syncthreads();
    }

    // ---- cross-quad butterfly merge (lanes {c,c+16,c+32,c+48} same vecs) ---
    {
#pragma unroll
        for (int delta = 16; delta <= 32; delta <<= 1) {
            float of1 = __shfl_xor(f1, delta, 64);
            int   oi1 = __shfl_xor(i1, delta, 64);
            float of2 = __shfl_xor(f2_, delta, 64);
            int   oi2 = __shfl_xor(i2_, delta, 64);
            bool o1_first = (of1 < f1) || (of1 == f1 && oi1 < i1);
            if (o1_first) {
                bool keep = (f1 < of2) || (f1 == of2 && i1 < oi2);
                f2_ = keep ? f1 : of2;
                i2_ = keep ? i1 : oi2;
                f1 = of1; i1 = oi1;
            } else {
                bool o1_second = (of1 < f2_) || (of1 == f2_ && oi1 < i2_);
                if (o1_second) { f2_ = of1; i2_ = oi1; }
            }
        }
        if (quad == 0) {   // lanes 0..15 hold final result for their vector
            const int vl = wave * 16 + l16;
            s_win[vl]  = i1;
            s_i1[vl]   = i1;
            s_i2[vl]   = i2_;
            s_flag[vl] = (f2_ - f1) < TAU;
        }
    }
    __syncthreads();

    // ---- parallel fp64 re-resolve: 4 lanes per vector, both candidates -----
    {
        const int vec = tid >> 2, sub = tid & 3;   // 64 vectors x 4 lanes
        if (s_flag[vec]) {
            const int i1c = s_i1[vec], i2c = s_i2[vec];
            const float* xr = xb + nbase + vec;
            const float* r1 = cb + (size_t)i1c * DIM;
            const float* r2 = cb + (size_t)i2c * DIM;
            double D1 = 0.0, D2 = 0.0;
#pragma unroll 4
            for (int i = 0; i < 16; ++i) {
                const int d = sub + 4 * i;
                double xd = (double)xr[(size_t)d * 1024];
                double t1 = xd - (double)r1[d]; D1 += t1 * t1;
                double t2 = xd - (double)r2[d]; D2 += t2 * t2;
            }
            D1 += __shfl_down(D1, 2, 64); D1 += __shfl_down(D1, 1, 64);
            D2 += __shfl_down(D2, 2, 64); D2 += __shfl_down(D2, 1, 64);
            if (sub == 0) {
                if (D2 < D1 || (D2 == D1 && i2c < i1c)) s_win[vec] = i2c;
            }
        }
    }
    __syncthreads();

    // ---- output: out[b, d, nbase+n] = cb[win[n]][d], coalesced over n ------
    {
        const int n    = tid & 63;            // 64 vectors
        const int dgrp = tid >> 6;            // 4 groups of 16 dims
        const float4* crow = (const float4*)(cb + (size_t)s_win[n] * DIM);
        float* op = out + (size_t)b * 65536 + nbase + n;
#pragma unroll
        for (int i = 0; i < 4; ++i) {
            const int d0 = dgrp * 16 + i * 4;
            float4 val = crow[d0 >> 2];
            op[(size_t)(d0 + 0) * 1024] = val.x;
            op[(size_t)(d0 + 1) * 1024] = val.y;
            op[(size_t)(d0 + 2) * 1024] = val.z;
            op[(size_t)(d0 + 3) * 1024] = val.w;
        }
    }
}

extern "C" void kernel_launch(void* const* d_in, const int* in_sizes, int n_in,
                              void* d_out, int out_size, void* d_ws, size_t ws_size,
                              hipStream_t stream) {
    const float* x  = (const float*)d_in[0];   // (64, 64, 32, 32) fp32
    const float* cb = (const float*)d_in[1];   // (512, 64) fp32
    float* out = (float*)d_out;

    // workspace: cbt (128 KB staged-tile codebook) | e2q (2 KB)
    unsigned short* cbt = (unsigned short*)d_ws;
    float*          e2q = (float*)(cbt + 8192 * 8);

    prep_kernel<<<640, 64, 0, stream>>>(cb, cbt, e2q);
    vq_main<<<NVEC / 64, 256, 0, stream>>>(x, cb, cbt, e2q, out);
}